// Round 5
// baseline (248.404 us; speedup 1.0000x reference)
//
#include <hip/hip_runtime.h>

#define NTOK 256
#define DIM  128
#define HD   32
#define NWIN 64

typedef __bf16 bf16x8 __attribute__((ext_vector_type(8)));
typedef __bf16 bf16x4 __attribute__((ext_vector_type(4)));
typedef float  f32x4  __attribute__((ext_vector_type(4)));

__device__ __forceinline__ float bf2f(unsigned short s) {
    union { unsigned u; float f; } x; x.u = ((unsigned)s) << 16; return x.f;
}
__device__ __forceinline__ unsigned f2bf_rne(float f) {
    union { float f; unsigned u; } x; x.f = f;
    return (x.u + 0x7FFF + ((x.u >> 16) & 1)) >> 16;
}
// relative-position table index for token pair (i, j)
__device__ __forceinline__ int rel_idx(int i, int j) {
    int di = i >> 6, hi = (i >> 3) & 7, wi = i & 7;
    int dj = j >> 6, hj = (j >> 3) & 7, wj = j & 7;
    return 225 * (di - dj + 3) + 15 * (hi - hj + 7) + (wi - wj + 7);
}

__device__ __forceinline__ int swz256(int row, int b) { return row * 256 + (b ^ ((row & 7) << 4)); }
__device__ __forceinline__ int swz64 (int row, int b) { return row * 64  + (b ^ (((row >> 1) & 3) << 4)); }
__device__ __forceinline__ int swzV  (int d,   int b) { return d   * 512 + (b ^ ((d & 7) << 4)); }

// ===================== SPLIT PATH =====================
// ws layout (bytes):
#define BIAS_OFF 0u            // 4*256*256 bf16   = 512 KB
#define MASK_OFF 0x80000u      // 64*256*256 bf16  = 8 MB
#define WBF_OFF  0x880000u     // 384*128 bf16     = 96 KB
#define QR_OFF   0x8A0000u     // 512*4*256*32 bf16 = 32 MB
#define KR_OFF   0x28A0000u
#define VT_OFF   0x48A0000u
#define NEED_SPLIT 0x68A0000u  // ~104.6 MB

// ---- prep: bias[h][i][j], maskbf[w][i][j], wbf[row][col] (all bf16) ----
__global__ void prep_kernel(const float* __restrict__ mask, const float* __restrict__ table,
                            const float* __restrict__ qkv_w,
                            unsigned short* __restrict__ bias, unsigned short* __restrict__ maskbf,
                            unsigned short* __restrict__ wbf) {
    int gid = blockIdx.x * 256 + threadIdx.x;
    if (gid < 262144) {
        int j = gid & 255, i = (gid >> 8) & 255, h = gid >> 16;
        bias[gid] = (unsigned short)f2bf_rne(table[rel_idx(i, j) * 4 + h]);
    } else if (gid < 262144 + 4194304) {
        int m = gid - 262144;
        maskbf[m] = (unsigned short)f2bf_rne(mask[m]);
    } else if (gid < 262144 + 4194304 + 49152) {
        int v = gid - 4456448;
        wbf[v] = (unsigned short)f2bf_rne(qkv_w[v]);
    }
}

// ---- projection: LDS-free streaming GEMM; Q,K row-major [bh][n][d], V transposed [bh][d][n] ----
__global__ __launch_bounds__(256, 8) void proj_kernel(
    const float* __restrict__ x, const unsigned short* __restrict__ wbf,
    const float* __restrict__ q_bias, const float* __restrict__ v_bias,
    unsigned short* __restrict__ qr, unsigned short* __restrict__ kr,
    unsigned short* __restrict__ vt) {
    const int tid = threadIdx.x;
    const int wv = tid >> 6, lane = tid & 63, lr = lane & 15, lg = lane >> 4;
    const int n0 = blockIdx.x * 64 + wv * 16;     // 2048 blocks x 4 waves x 16 tokens
    const int bb = n0 >> 8;
    const int nloc0 = n0 & 255;
    const float SCALE = 0.17677669529663687f;     // 1/sqrt(32)

    // A-fragments: x[n0+lr][kk*32 + lg*8 + e], fp32 -> bf16
    const float* xrow = x + (size_t)(n0 + lr) * DIM;
    bf16x8 xa[4];
    #pragma unroll
    for (int kk = 0; kk < 4; ++kk) {
        const float* p = xrow + kk * 32 + lg * 8;
        float4 f0 = *(const float4*)(p);
        float4 f1 = *(const float4*)(p + 4);
        union { bf16x8 v; __bf16 e[8]; } u8;
        u8.e[0] = (__bf16)f0.x; u8.e[1] = (__bf16)f0.y; u8.e[2] = (__bf16)f0.z; u8.e[3] = (__bf16)f0.w;
        u8.e[4] = (__bf16)f1.x; u8.e[5] = (__bf16)f1.y; u8.e[6] = (__bf16)f1.z; u8.e[7] = (__bf16)f1.w;
        xa[kk] = u8.v;
    }
    #pragma unroll
    for (int h = 0; h < 4; ++h) {
        const size_t bh = (size_t)(bb * 4 + h);
        #pragma unroll
        for (int nt = 0; nt < 6; ++nt) {
            const int sec = nt >> 1;              // 0=Q 1=K 2=V
            const int wrow = sec * 128 + h * 32 + (nt & 1) * 16 + lr;
            f32x4 acc = {0.f, 0.f, 0.f, 0.f};
            #pragma unroll
            for (int kk = 0; kk < 4; ++kk) {
                bf16x8 wb = *(const bf16x8*)(wbf + wrow * DIM + kk * 32 + lg * 8);
                acc = __builtin_amdgcn_mfma_f32_16x16x32_bf16(xa[kk], wb, acc, 0, 0, 0);
            }
            const int d = (nt & 1) * 16 + lr;
            if (sec == 2) {
                float b = v_bias[h * 32 + d];
                union { bf16x4 v; __bf16 e[4]; } u4;
                #pragma unroll
                for (int r = 0; r < 4; ++r) u4.e[r] = (__bf16)(acc[r] + b);
                int nb = nloc0 + lg * 4;          // C layout: row = lg*4 + r
                *(bf16x4*)(vt + (bh * 32 + d) * 256 + nb) = u4.v;
            } else {
                float b = (sec == 0) ? q_bias[h * 32 + d] : 0.f;
                unsigned short* dst = (sec == 0) ? qr : kr;
                #pragma unroll
                for (int r = 0; r < 4; ++r) {
                    int n = nloc0 + lg * 4 + r;
                    float val = acc[r] + b;
                    if (sec == 0) val *= SCALE;
                    dst[(bh * 256 + n) * 32 + d] = (unsigned short)f2bf_rne(val);
                }
            }
        }
    }
}

// ---- attention: per (bb,h), 48 KB LDS, one barrier, tt-sequential ----
#define K_L 0
#define V_L 16384
#define P_L 32768

__global__ __launch_bounds__(512, 4) void attn2_kernel(
    const unsigned short* __restrict__ qr, const unsigned short* __restrict__ kr,
    const unsigned short* __restrict__ vt, const unsigned short* __restrict__ bias,
    const unsigned short* __restrict__ maskbf, float* __restrict__ out) {
    __shared__ char smem[49152];
    const int tid = threadIdx.x;
    const int bid = blockIdx.x;
    // bid = rep*256 + pair: the 8 batch-reps of a (window,head) share bid%8 -> same XCD L2
    const int rep = bid >> 8, pair = bid & 255;
    const int w_idx = pair >> 2, h = pair & 3;
    const int bb = rep * 64 + w_idx;
    const size_t bh = (size_t)(bb * 4 + h);

    // ---- stage K [256][32] -> swizzled LDS ----
    {
        int row = tid >> 1, half = tid & 1;
        const unsigned short* src = kr + (bh * 256 + row) * 32 + half * 16;
        bf16x8 a = *(const bf16x8*)(src);
        bf16x8 b = *(const bf16x8*)(src + 8);
        *(bf16x8*)(smem + K_L + swz64(row, half * 32)) = a;
        *(bf16x8*)(smem + K_L + swz64(row, half * 32 + 16)) = b;
    }
    // ---- stage Vt [32][256] -> swizzled LDS ----
    {
        int d = tid >> 4, seg = tid & 15;
        const unsigned short* src = vt + (bh * 32 + d) * 256 + seg * 16;
        bf16x8 a = *(const bf16x8*)(src);
        bf16x8 b = *(const bf16x8*)(src + 8);
        *(bf16x8*)(smem + V_L + swzV(d, seg * 32)) = a;
        *(bf16x8*)(smem + V_L + swzV(d, seg * 32 + 16)) = b;
    }
    __syncthreads();

    const int w = tid >> 6, lane = tid & 63, lr = lane & 15, lg = lane >> 4;
    const unsigned short* brow_base = bias + ((size_t)h << 16);
    const unsigned short* mrow_base = maskbf + ((size_t)w_idx << 16);
    char* pbuf = smem + P_L + w * 2048;

    #pragma unroll
    for (int tt = 0; tt < 2; ++tt) {
        const int rg = w * 32 + tt * 16 + lr;
        // Q fragment direct from global (16B/lane)
        bf16x8 qf = *(const bf16x8*)(qr + (bh * 256 + rg) * 32 + lg * 8);

        // S^T = K * Q^T : lane holds S[q=lr][j = kt*16 + lg*4 + r]
        f32x4 st[16];
        #pragma unroll
        for (int kt = 0; kt < 16; ++kt) {
            bf16x8 kf = *(bf16x8*)(smem + K_L + swz64(kt * 16 + lr, lg * 16));
            f32x4 z = {0.f, 0.f, 0.f, 0.f};
            st[kt] = __builtin_amdgcn_mfma_f32_16x16x32_bf16(kf, qf, z, 0, 0, 0);
        }
        // + bias + mask, row max
        const unsigned short* brow = brow_base + rg * 256 + lg * 4;
        const unsigned short* mrow = mrow_base + rg * 256 + lg * 4;
        float mx = -3.0e38f;
        #pragma unroll
        for (int kt = 0; kt < 16; ++kt) {
            ushort4 b4 = *(const ushort4*)(brow + kt * 16);
            ushort4 m4 = *(const ushort4*)(mrow + kt * 16);
            st[kt][0] += bf2f(b4.x) + bf2f(m4.x);
            st[kt][1] += bf2f(b4.y) + bf2f(m4.y);
            st[kt][2] += bf2f(b4.z) + bf2f(m4.z);
            st[kt][3] += bf2f(b4.w) + bf2f(m4.w);
            mx = fmaxf(mx, fmaxf(fmaxf(st[kt][0], st[kt][1]), fmaxf(st[kt][2], st[kt][3])));
        }
        mx = fmaxf(mx, __shfl_xor(mx, 16));
        mx = fmaxf(mx, __shfl_xor(mx, 32));
        float sum = 0.f;
        #pragma unroll
        for (int kt = 0; kt < 16; ++kt) {
            #pragma unroll
            for (int c = 0; c < 4; ++c) {
                float e = __expf(st[kt][c] - mx);
                st[kt][c] = e;
                sum += e;
            }
        }
        sum += __shfl_xor(sum, 16);
        sum += __shfl_xor(sum, 32);
        float inv = 1.0f / sum;

        // PV: per-wave P staging (16 rows x 32 j per step), MFMA with Vt
        f32x4 oacc[2];
        oacc[0] = (f32x4){0.f, 0.f, 0.f, 0.f};
        oacc[1] = (f32x4){0.f, 0.f, 0.f, 0.f};
        #pragma unroll
        for (int s = 0; s < 8; ++s) {
            #pragma unroll
            for (int half = 0; half < 2; ++half) {
                f32x4 p = st[2 * s + half];
                union { bf16x4 v; __bf16 e[4]; } u4;
                u4.e[0] = (__bf16)(p[0] * inv);
                u4.e[1] = (__bf16)(p[1] * inv);
                u4.e[2] = (__bf16)(p[2] * inv);
                u4.e[3] = (__bf16)(p[3] * inv);
                *(bf16x4*)(pbuf + swz64(lr, half * 32 + lg * 8)) = u4.v;
            }
            bf16x8 af = *(bf16x8*)(pbuf + swz64(lr, lg * 16));
            #pragma unroll
            for (int u = 0; u < 2; ++u) {
                bf16x8 vf = *(bf16x8*)(smem + V_L + swzV(u * 16 + lr, s * 64 + lg * 16));
                oacc[u] = __builtin_amdgcn_mfma_f32_16x16x32_bf16(af, vf, oacc[u], 0, 0, 0);
            }
        }
        // out[bb][n][h*32+d]
        float* op = out + (((size_t)bb * 256 + w * 32 + tt * 16) * 128) + h * 32;
        #pragma unroll
        for (int u = 0; u < 2; ++u)
            #pragma unroll
            for (int r = 0; r < 4; ++r)
                op[(lg * 4 + r) * 128 + u * 16 + lr] = oacc[u][r];
    }
}

// ===================== FALLBACK (round-4 proven fused path) =====================
#define X_OFF 0
#define W_OFF 65536
#define Q_OFF 90112
#define K_OFF 106496
#define V_OFF 122880
#define LDS_BYTES 139264

__global__ void comb_kernel(const float* __restrict__ mask, const float* __restrict__ table,
                            unsigned short* __restrict__ comb) {
    int gid = blockIdx.x * 256 + threadIdx.x;
    int j = gid & 255, i = (gid >> 8) & 255, h = (gid >> 16) & 3, w = gid >> 18;
    float v = mask[(w << 16) | (i << 8) | j] + table[rel_idx(i, j) * 4 + h];
    comb[gid] = (unsigned short)f2bf_rne(v);
}
__global__ void bias_kernel(const float* __restrict__ table, unsigned short* __restrict__ bias) {
    int gid = blockIdx.x * 256 + threadIdx.x;
    int j = gid & 255, i = (gid >> 8) & 255, h = gid >> 16;
    bias[gid] = (unsigned short)f2bf_rne(table[rel_idx(i, j) * 4 + h]);
}

template <int MODE>
__global__ __launch_bounds__(512, 2) void attn_kernel(
    const float* __restrict__ x, const float* __restrict__ qkv_w,
    const float* __restrict__ q_bias, const float* __restrict__ v_bias,
    const unsigned short* __restrict__ aux16, const float* __restrict__ mask,
    const float* __restrict__ table, float* __restrict__ out) {
    extern __shared__ char smem[];
    const int tid = threadIdx.x;
    const int bb = blockIdx.x >> 2, h = blockIdx.x & 3;
    const int w = tid >> 6, lane = tid & 63, lr = lane & 15, lg = lane >> 4;

    const float* xp = x + (size_t)bb * (NTOK * DIM);
    #pragma unroll
    for (int it = 0; it < 8; ++it) {
        int base = (it * 512 + tid) * 8;
        int row = base >> 7, col = base & 127;
        float4 f0 = *(const float4*)(xp + base);
        float4 f1 = *(const float4*)(xp + base + 4);
        union { bf16x8 v; __bf16 e[8]; } u8;
        u8.e[0] = (__bf16)f0.x; u8.e[1] = (__bf16)f0.y; u8.e[2] = (__bf16)f0.z; u8.e[3] = (__bf16)f0.w;
        u8.e[4] = (__bf16)f1.x; u8.e[5] = (__bf16)f1.y; u8.e[6] = (__bf16)f1.z; u8.e[7] = (__bf16)f1.w;
        *(bf16x8*)(smem + X_OFF + swz256(row, col * 2)) = u8.v;
    }
    #pragma unroll
    for (int it = 0; it < 3; ++it) {
        int base = (it * 512 + tid) * 8;
        int row = base >> 7, col = base & 127;
        int sec = row >> 5, r5 = row & 31;
        const float* wp = qkv_w + ((sec * 128 + h * 32 + r5) * DIM + col);
        float4 f0 = *(const float4*)(wp);
        float4 f1 = *(const float4*)(wp + 4);
        union { bf16x8 v; __bf16 e[8]; } u8;
        u8.e[0] = (__bf16)f0.x; u8.e[1] = (__bf16)f0.y; u8.e[2] = (__bf16)f0.z; u8.e[3] = (__bf16)f0.w;
        u8.e[4] = (__bf16)f1.x; u8.e[5] = (__bf16)f1.y; u8.e[6] = (__bf16)f1.z; u8.e[7] = (__bf16)f1.w;
        *(bf16x8*)(smem + W_OFF + swz256(row, col * 2)) = u8.v;
    }
    __syncthreads();

    const float SCALE = 0.17677669529663687f;
    #pragma unroll
    for (int mi = 0; mi < 2; ++mi) {
        int mt = w * 2 + mi;
        bf16x8 xa[4];
        #pragma unroll
        for (int kk = 0; kk < 4; ++kk)
            xa[kk] = *(bf16x8*)(smem + X_OFF + swz256(mt * 16 + lr, kk * 64 + lg * 16));
        #pragma unroll
        for (int nt = 0; nt < 6; ++nt) {
            f32x4 acc = {0.f, 0.f, 0.f, 0.f};
            #pragma unroll
            for (int kk = 0; kk < 4; ++kk) {
                bf16x8 wb = *(bf16x8*)(smem + W_OFF + swz256(nt * 16 + lr, kk * 64 + lg * 16));
                acc = __builtin_amdgcn_mfma_f32_16x16x32_bf16(xa[kk], wb, acc, 0, 0, 0);
            }
            int sec = nt >> 1;
            int d = (nt & 1) * 16 + lr;
            float bias = 0.f;
            if (sec == 0) bias = q_bias[h * 32 + d];
            if (sec == 2) bias = v_bias[h * 32 + d];
            #pragma unroll
            for (int r = 0; r < 4; ++r) {
                int row = mt * 16 + lg * 4 + r;
                float val = acc[r] + bias;
                if (sec == 0) {
                    val *= SCALE;
                    *(__bf16*)(smem + Q_OFF + swz64(row, d * 2)) = (__bf16)val;
                } else if (sec == 1) {
                    *(__bf16*)(smem + K_OFF + swz64(row, d * 2)) = (__bf16)val;
                } else {
                    *(__bf16*)(smem + V_OFF + swzV(d, row * 2)) = (__bf16)val;
                }
            }
        }
    }
    __syncthreads();

    bf16x8 qf[2];
    #pragma unroll
    for (int tt = 0; tt < 2; ++tt)
        qf[tt] = *(bf16x8*)(smem + Q_OFF + swz64(w * 32 + tt * 16 + lr, lg * 16));

    f32x4 st[2][16];
    #pragma unroll
    for (int kt = 0; kt < 16; ++kt) {
        bf16x8 kf = *(bf16x8*)(smem + K_OFF + swz64(kt * 16 + lr, lg * 16));
        f32x4 z = {0.f, 0.f, 0.f, 0.f};
        st[0][kt] = __builtin_amdgcn_mfma_f32_16x16x32_bf16(kf, qf[0], z, 0, 0, 0);
        st[1][kt] = __builtin_amdgcn_mfma_f32_16x16x32_bf16(kf, qf[1], z, 0, 0, 0);
    }

    const int w_idx = bb & 63;
    float inv[2];
    #pragma unroll
    for (int tt = 0; tt < 2; ++tt) {
        int rg = w * 32 + tt * 16 + lr;
        float mx = -3.0e38f;
        #pragma unroll
        for (int kt = 0; kt < 16; ++kt) {
            if (MODE == 0) {
                const unsigned short* crow =
                    aux16 + (((size_t)(w_idx * 4 + h)) << 16) + rg * 256 + lg * 4;
                ushort4 c4 = *(const ushort4*)(crow + kt * 16);
                st[tt][kt][0] += bf2f(c4.x);
                st[tt][kt][1] += bf2f(c4.y);
                st[tt][kt][2] += bf2f(c4.z);
                st[tt][kt][3] += bf2f(c4.w);
            } else if (MODE == 1) {
                const unsigned short* brow = aux16 + (((size_t)h) << 16) + rg * 256 + lg * 4;
                const float* mrow = mask + (((size_t)w_idx) << 16) + rg * 256 + lg * 4;
                ushort4 c4 = *(const ushort4*)(brow + kt * 16);
                float4 m4 = *(const float4*)(mrow + kt * 16);
                st[tt][kt][0] += bf2f(c4.x) + m4.x;
                st[tt][kt][1] += bf2f(c4.y) + m4.y;
                st[tt][kt][2] += bf2f(c4.z) + m4.z;
                st[tt][kt][3] += bf2f(c4.w) + m4.w;
            } else {
                const float* mrow = mask + (((size_t)w_idx) << 16) + rg * 256 + lg * 4;
                float4 m4 = *(const float4*)(mrow + kt * 16);
                #pragma unroll
                for (int c = 0; c < 4; ++c) {
                    int j = kt * 16 + lg * 4 + c;
                    float m = (c == 0) ? m4.x : (c == 1) ? m4.y : (c == 2) ? m4.z : m4.w;
                    st[tt][kt][c] += table[rel_idx(rg, j) * 4 + h] + m;
                }
            }
            mx = fmaxf(mx, fmaxf(fmaxf(st[tt][kt][0], st[tt][kt][1]),
                                 fmaxf(st[tt][kt][2], st[tt][kt][3])));
        }
        mx = fmaxf(mx, __shfl_xor(mx, 16));
        mx = fmaxf(mx, __shfl_xor(mx, 32));
        float sum = 0.f;
        #pragma unroll
        for (int kt = 0; kt < 16; ++kt) {
            #pragma unroll
            for (int c = 0; c < 4; ++c) {
                float e = __expf(st[tt][kt][c] - mx);
                st[tt][kt][c] = e;
                sum += e;
            }
        }
        sum += __shfl_xor(sum, 16);
        sum += __shfl_xor(sum, 32);
        inv[tt] = 1.0f / sum;
    }

    char* pbuf = smem + X_OFF + w * 2048;
    f32x4 oacc[2][2];
    #pragma unroll
    for (int tt = 0; tt < 2; ++tt)
        #pragma unroll
        for (int u = 0; u < 2; ++u)
            oacc[tt][u] = (f32x4){0.f, 0.f, 0.f, 0.f};

    #pragma unroll
    for (int s = 0; s < 8; ++s) {
        #pragma unroll
        for (int tt = 0; tt < 2; ++tt) {
            #pragma unroll
            for (int half = 0; half < 2; ++half) {
                f32x4 p = st[tt][2 * s + half];
                union { bf16x4 v; __bf16 e[4]; } u4;
                u4.e[0] = (__bf16)(p[0] * inv[tt]);
                u4.e[1] = (__bf16)(p[1] * inv[tt]);
                u4.e[2] = (__bf16)(p[2] * inv[tt]);
                u4.e[3] = (__bf16)(p[3] * inv[tt]);
                *(bf16x4*)(pbuf + swz64(tt * 16 + lr, half * 32 + lg * 8)) = u4.v;
            }
        }
        bf16x8 vf[2];
        #pragma unroll
        for (int u = 0; u < 2; ++u)
            vf[u] = *(bf16x8*)(smem + V_OFF + swzV(u * 16 + lr, s * 64 + lg * 16));
        #pragma unroll
        for (int tt = 0; tt < 2; ++tt) {
            bf16x8 af = *(bf16x8*)(pbuf + swz64(tt * 16 + lr, lg * 16));
            #pragma unroll
            for (int u = 0; u < 2; ++u)
                oacc[tt][u] = __builtin_amdgcn_mfma_f32_16x16x32_bf16(af, vf[u], oacc[tt][u], 0, 0, 0);
        }
    }

    float* op = out + (((size_t)bb * 256 + w * 32) * 128) + h * 32;
    #pragma unroll
    for (int tt = 0; tt < 2; ++tt)
        #pragma unroll
        for (int u = 0; u < 2; ++u)
            #pragma unroll
            for (int r = 0; r < 4; ++r)
                op[(tt * 16 + lg * 4 + r) * 128 + u * 16 + lr] = oacc[tt][u][r];
}

extern "C" void kernel_launch(void* const* d_in, const int* in_sizes, int n_in,
                              void* d_out, int out_size, void* d_ws, size_t ws_size,
                              hipStream_t stream) {
    const float* x      = (const float*)d_in[0];
    const float* mask   = (const float*)d_in[1];
    const float* qkv_w  = (const float*)d_in[2];
    const float* q_bias = (const float*)d_in[3];
    const float* v_bias = (const float*)d_in[4];
    const float* table  = (const float*)d_in[5];
    float* out = (float*)d_out;
    (void)in_sizes; (void)n_in; (void)out_size;

    if (ws_size >= (size_t)NEED_SPLIT) {
        char* ws = (char*)d_ws;
        unsigned short* bias   = (unsigned short*)(ws + BIAS_OFF);
        unsigned short* maskbf = (unsigned short*)(ws + MASK_OFF);
        unsigned short* wbf    = (unsigned short*)(ws + WBF_OFF);
        unsigned short* qr     = (unsigned short*)(ws + QR_OFF);
        unsigned short* kr     = (unsigned short*)(ws + KR_OFF);
        unsigned short* vt     = (unsigned short*)(ws + VT_OFF);
        prep_kernel<<<17600, 256, 0, stream>>>(mask, table, qkv_w, bias, maskbf, wbf);
        proj_kernel<<<2048, 256, 0, stream>>>(x, wbf, q_bias, v_bias, qr, kr, vt);
        attn2_kernel<<<2048, 512, 0, stream>>>(qr, kr, vt, bias, maskbf, out);
        return;
    }

    const size_t NEED_COMB = (size_t)NWIN * 4 * 256 * 256 * 2;  // 32 MB
    const size_t NEED_BIAS = (size_t)4 * 256 * 256 * 2;         // 512 KB
    if (ws_size >= NEED_COMB) {
        unsigned short* comb = (unsigned short*)d_ws;
        comb_kernel<<<65536, 256, 0, stream>>>(mask, table, comb);
        hipFuncSetAttribute((const void*)attn_kernel<0>,
                            hipFuncAttributeMaxDynamicSharedMemorySize, LDS_BYTES);
        attn_kernel<0><<<2048, 512, LDS_BYTES, stream>>>(x, qkv_w, q_bias, v_bias,
                                                         comb, mask, table, out);
    } else if (ws_size >= NEED_BIAS) {
        unsigned short* bias = (unsigned short*)d_ws;
        bias_kernel<<<1024, 256, 0, stream>>>(table, bias);
        hipFuncSetAttribute((const void*)attn_kernel<1>,
                            hipFuncAttributeMaxDynamicSharedMemorySize, LDS_BYTES);
        attn_kernel<1><<<2048, 512, LDS_BYTES, stream>>>(x, qkv_w, q_bias, v_bias,
                                                         bias, mask, table, out);
    } else {
        hipFuncSetAttribute((const void*)attn_kernel<2>,
                            hipFuncAttributeMaxDynamicSharedMemorySize, LDS_BYTES);
        attn_kernel<2><<<2048, 512, LDS_BYTES, stream>>>(x, qkv_w, q_bias, v_bias,
                                                         nullptr, mask, table, out);
    }
}

// Round 6
// 245.925 us; speedup vs baseline: 1.0101x; 1.0101x over previous
//
#include <hip/hip_runtime.h>

#define NTOK 256
#define DIM  128
#define NWIN 64

typedef __bf16 bf16x8 __attribute__((ext_vector_type(8)));
typedef __bf16 bf16x4 __attribute__((ext_vector_type(4)));
typedef float  f32x4  __attribute__((ext_vector_type(4)));

__device__ __forceinline__ float bf2f(unsigned short s) {
    union { unsigned u; float f; } x; x.u = ((unsigned)s) << 16; return x.f;
}
__device__ __forceinline__ unsigned f2bf_rne(float f) {
    union { float f; unsigned u; } x; x.f = f;
    return (x.u + 0x7FFF + ((x.u >> 16) & 1)) >> 16;
}
__device__ __forceinline__ unsigned pack2bf(float lo, float hi) {
    __bf16 a = (__bf16)lo, b = (__bf16)hi;
    unsigned short ua = *(unsigned short*)&a, ub = *(unsigned short*)&b;
    return ((unsigned)ub << 16) | ua;
}
__device__ __forceinline__ int rel_idx(int i, int j) {
    int di = i >> 6, hi = (i >> 3) & 7, wi = i & 7;
    int dj = j >> 6, hj = (j >> 3) & 7, wj = j & 7;
    return 225 * (di - dj + 3) + 15 * (hi - hj + 7) + (wi - wj + 7);
}
__device__ __forceinline__ int swz64(int row, int b) { return row * 64  + (b ^ (((row >> 1) & 3) << 4)); }
__device__ __forceinline__ int swzV (int d,   int b) { return d   * 512 + (b ^ ((d & 7) << 4)); }

// ===================== ws layout =====================
#define BIAS_OFF 0u            // 4*256*256 bf16   = 512 KB
#define MASK_OFF 0x80000u      // 64*256*256 bf16  = 8 MB
#define WBF_OFF  0x880000u     // 384*128 bf16     = 96 KB
#define NEED3    0x898000u     // ~8.6 MB

// ---- prep: bias[h][i][j], maskbf[w][i][j], wbf[row][col] (all bf16) ----
__global__ void prep_kernel(const float* __restrict__ mask, const float* __restrict__ table,
                            const float* __restrict__ qkv_w,
                            unsigned short* __restrict__ bias, unsigned short* __restrict__ maskbf,
                            unsigned short* __restrict__ wbf) {
    int gid = blockIdx.x * 256 + threadIdx.x;
    if (gid < 262144) {
        int j = gid & 255, i = (gid >> 8) & 255, h = gid >> 16;
        bias[gid] = (unsigned short)f2bf_rne(table[rel_idx(i, j) * 4 + h]);
    } else if (gid < 262144 + 4194304) {
        int m = gid - 262144;
        maskbf[m] = (unsigned short)f2bf_rne(mask[m]);
    } else if (gid < 262144 + 4194304 + 49152) {
        int v = gid - 4456448;
        wbf[v] = (unsigned short)f2bf_rne(qkv_w[v]);
    }
}

// ---- fused projection + attention: one block per (bb, h), 48 KB LDS, one barrier ----
#define Q_L 0
#define K_L 16384
#define V_L 32768

__global__ __launch_bounds__(512, 4) void attn3_kernel(
    const float* __restrict__ x, const unsigned short* __restrict__ wbf,
    const float* __restrict__ q_bias, const float* __restrict__ v_bias,
    const unsigned short* __restrict__ bias, const unsigned short* __restrict__ maskbf,
    float* __restrict__ out) {
    __shared__ char smem[49152];
    const int tid = threadIdx.x;

    // XCD chunk swizzle: physical p -> xcd chunk c = p&7 owns w_idx in [c*8, c*8+8)
    const int p = blockIdx.x;
    const int logical = (p & 7) * 256 + (p >> 3);
    const int c = logical >> 8, kk_ = logical & 255;
    const int rep = kk_ >> 5, wq = c * 8 + ((kk_ >> 2) & 7), h = kk_ & 3;
    const int bb = rep * 64 + wq;

    const int w = tid >> 6, lane = tid & 63, lr = lane & 15, lg = lane >> 4;
    const float SCALE = 0.17677669529663687f;       // 1/sqrt(32)
    const float qb0 = q_bias[h * 32 + lr],      qb1 = q_bias[h * 32 + 16 + lr];
    const float vb0 = v_bias[h * 32 + lr],      vb1 = v_bias[h * 32 + 16 + lr];

    // ---- projection: wave owns tokens [w*32, w*32+32); x A-frags from global ----
    #pragma unroll
    for (int mi = 0; mi < 2; ++mi) {
        const int mt = w * 2 + mi;
        const float* xrow = x + ((size_t)bb * 256 + mt * 16 + lr) * DIM;
        bf16x8 xa[4];
        #pragma unroll
        for (int kk = 0; kk < 4; ++kk) {
            const float* xp2 = xrow + kk * 32 + lg * 8;
            float4 f0 = *(const float4*)(xp2);
            float4 f1 = *(const float4*)(xp2 + 4);
            union { bf16x8 v; __bf16 e[8]; } u8;
            u8.e[0] = (__bf16)f0.x; u8.e[1] = (__bf16)f0.y; u8.e[2] = (__bf16)f0.z; u8.e[3] = (__bf16)f0.w;
            u8.e[4] = (__bf16)f1.x; u8.e[5] = (__bf16)f1.y; u8.e[6] = (__bf16)f1.z; u8.e[7] = (__bf16)f1.w;
            xa[kk] = u8.v;
        }
        #pragma unroll
        for (int nt = 0; nt < 6; ++nt) {
            const int sec = nt >> 1;                // 0=Q 1=K 2=V
            const int wrow = sec * 128 + h * 32 + (nt & 1) * 16 + lr;
            f32x4 acc = {0.f, 0.f, 0.f, 0.f};
            #pragma unroll
            for (int kk = 0; kk < 4; ++kk) {
                bf16x8 wb = *(const bf16x8*)(wbf + wrow * DIM + kk * 32 + lg * 8);
                acc = __builtin_amdgcn_mfma_f32_16x16x32_bf16(xa[kk], wb, acc, 0, 0, 0);
            }
            const int d = (nt & 1) * 16 + lr;
            if (sec == 0) {
                float b = (nt & 1) ? qb1 : qb0;
                #pragma unroll
                for (int r = 0; r < 4; ++r) {
                    int row = mt * 16 + lg * 4 + r;
                    *(__bf16*)(smem + Q_L + swz64(row, d * 2)) = (__bf16)((acc[r] + b) * SCALE);
                }
            } else if (sec == 1) {
                #pragma unroll
                for (int r = 0; r < 4; ++r) {
                    int row = mt * 16 + lg * 4 + r;
                    *(__bf16*)(smem + K_L + swz64(row, d * 2)) = (__bf16)acc[r];
                }
            } else {
                float b = (nt & 1) ? vb1 : vb0;
                union { bf16x4 v; __bf16 e[4]; } u4;
                #pragma unroll
                for (int r = 0; r < 4; ++r) u4.e[r] = (__bf16)(acc[r] + b);
                int nb = mt * 16 + lg * 4;          // 4 consecutive tokens -> 8B store
                *(bf16x4*)(smem + V_L + swzV(d, nb * 2)) = u4.v;
            }
        }
    }
    __syncthreads();

    const unsigned short* brow_base = bias + ((size_t)h << 16);
    const unsigned short* mrow_base = maskbf + ((size_t)wq << 16);

    #pragma unroll
    for (int tt = 0; tt < 2; ++tt) {
        const int rg = w * 32 + tt * 16 + lr;
        // Q B-frag (written by this same wave pre-barrier)
        bf16x8 qf = *(bf16x8*)(smem + Q_L + swz64(rg, lg * 16));

        // S^T = K * Q^T : lane holds S[q=lr][j = kt*16 + lg*4 + r]
        f32x4 st[16];
        #pragma unroll
        for (int kt = 0; kt < 16; ++kt) {
            bf16x8 kf = *(bf16x8*)(smem + K_L + swz64(kt * 16 + lr, lg * 16));
            f32x4 z = {0.f, 0.f, 0.f, 0.f};
            st[kt] = __builtin_amdgcn_mfma_f32_16x16x32_bf16(kf, qf, z, 0, 0, 0);
        }
        // + bias + mask (bf16, L2-resident), row max
        const unsigned short* brow = brow_base + rg * 256 + lg * 4;
        const unsigned short* mrow = mrow_base + rg * 256 + lg * 4;
        float mx = -3.0e38f;
        #pragma unroll
        for (int kt = 0; kt < 16; ++kt) {
            ushort4 b4 = *(const ushort4*)(brow + kt * 16);
            ushort4 m4 = *(const ushort4*)(mrow + kt * 16);
            st[kt][0] += bf2f(b4.x) + bf2f(m4.x);
            st[kt][1] += bf2f(b4.y) + bf2f(m4.y);
            st[kt][2] += bf2f(b4.z) + bf2f(m4.z);
            st[kt][3] += bf2f(b4.w) + bf2f(m4.w);
            mx = fmaxf(mx, fmaxf(fmaxf(st[kt][0], st[kt][1]), fmaxf(st[kt][2], st[kt][3])));
        }
        mx = fmaxf(mx, __shfl_xor(mx, 16));
        mx = fmaxf(mx, __shfl_xor(mx, 32));
        float sum = 0.f;
        #pragma unroll
        for (int kt = 0; kt < 16; ++kt) {
            #pragma unroll
            for (int cc = 0; cc < 4; ++cc) {
                float e = __expf(st[kt][cc] - mx);
                st[kt][cc] = e;
                sum += e;
            }
        }
        sum += __shfl_xor(sum, 16);
        sum += __shfl_xor(sum, 32);
        float inv = 1.0f / sum;

        // pack unnormalized P to bf16 pairs (bounded by 1 after max-sub)
        unsigned pk[16][2];
        #pragma unroll
        for (int kt = 0; kt < 16; ++kt) {
            pk[kt][0] = pack2bf(st[kt][0], st[kt][1]);
            pk[kt][1] = pack2bf(st[kt][2], st[kt][3]);
        }

        // PV via in-register regroup: af[e] = P[q=lr][j = jt*32 + lg*8 + e]
        // source lane = lr + 16*((2*lg + (e>>2)) & 3), kt = 2*jt + (lg>>1)
        f32x4 oacc[2];
        oacc[0] = (f32x4){0.f, 0.f, 0.f, 0.f};
        oacc[1] = (f32x4){0.f, 0.f, 0.f, 0.f};
        const int s0 = lr + ((lg & 1) << 5);
        const bool hiSel = (lg >= 2);
        #pragma unroll
        for (int jt = 0; jt < 8; ++jt) {
            unsigned a0 = pk[2 * jt][0],     a1 = pk[2 * jt][1];
            unsigned b0 = pk[2 * jt + 1][0], b1 = pk[2 * jt + 1][1];
            unsigned wA0 = __shfl(a0, s0),      wA1 = __shfl(a1, s0);
            unsigned wA2 = __shfl(a0, s0 + 16), wA3 = __shfl(a1, s0 + 16);
            unsigned wB0 = __shfl(b0, s0),      wB1 = __shfl(b1, s0);
            unsigned wB2 = __shfl(b0, s0 + 16), wB3 = __shfl(b1, s0 + 16);
            union { unsigned u[4]; bf16x8 v; } afu;
            afu.u[0] = hiSel ? wB0 : wA0;
            afu.u[1] = hiSel ? wB1 : wA1;
            afu.u[2] = hiSel ? wB2 : wA2;
            afu.u[3] = hiSel ? wB3 : wA3;
            #pragma unroll
            for (int u2 = 0; u2 < 2; ++u2) {
                bf16x8 vf = *(bf16x8*)(smem + V_L + swzV(u2 * 16 + lr, jt * 64 + lg * 16));
                oacc[u2] = __builtin_amdgcn_mfma_f32_16x16x32_bf16(afu.v, vf, oacc[u2], 0, 0, 0);
            }
        }
        // normalize post-PV: inv for output row lg*4+r lives at lane (lg*4+r)
        float invq[4];
        #pragma unroll
        for (int r = 0; r < 4; ++r) invq[r] = __shfl(inv, lg * 4 + r);

        float* op = out + (((size_t)bb * 256 + w * 32 + tt * 16) * 128) + h * 32;
        #pragma unroll
        for (int u2 = 0; u2 < 2; ++u2)
            #pragma unroll
            for (int r = 0; r < 4; ++r)
                op[(lg * 4 + r) * 128 + u2 * 16 + lr] = oacc[u2][r] * invq[r];
    }
}

// ===================== fallback (tiny ws): round-4 proven fused path =====================
#define X_OFF 0
#define W_OFF 65536
#define QF_OFF 90112
#define KF_OFF 106496
#define VF_OFF 122880
#define LDS_BYTES 139264

__device__ __forceinline__ int swz256(int row, int b) { return row * 256 + (b ^ ((row & 7) << 4)); }

__global__ void bias_kernel(const float* __restrict__ table, unsigned short* __restrict__ bias) {
    int gid = blockIdx.x * 256 + threadIdx.x;
    int j = gid & 255, i = (gid >> 8) & 255, h = gid >> 16;
    bias[gid] = (unsigned short)f2bf_rne(table[rel_idx(i, j) * 4 + h]);
}

template <int MODE>
__global__ __launch_bounds__(512, 2) void attn_kernel(
    const float* __restrict__ x, const float* __restrict__ qkv_w,
    const float* __restrict__ q_bias, const float* __restrict__ v_bias,
    const unsigned short* __restrict__ aux16, const float* __restrict__ mask,
    const float* __restrict__ table, float* __restrict__ out) {
    extern __shared__ char smem[];
    const int tid = threadIdx.x;
    const int bb = blockIdx.x >> 2, h = blockIdx.x & 3;
    const int w = tid >> 6, lane = tid & 63, lr = lane & 15, lg = lane >> 4;

    const float* xp = x + (size_t)bb * (NTOK * DIM);
    #pragma unroll
    for (int it = 0; it < 8; ++it) {
        int base = (it * 512 + tid) * 8;
        int row = base >> 7, col = base & 127;
        float4 f0 = *(const float4*)(xp + base);
        float4 f1 = *(const float4*)(xp + base + 4);
        union { bf16x8 v; __bf16 e[8]; } u8;
        u8.e[0] = (__bf16)f0.x; u8.e[1] = (__bf16)f0.y; u8.e[2] = (__bf16)f0.z; u8.e[3] = (__bf16)f0.w;
        u8.e[4] = (__bf16)f1.x; u8.e[5] = (__bf16)f1.y; u8.e[6] = (__bf16)f1.z; u8.e[7] = (__bf16)f1.w;
        *(bf16x8*)(smem + X_OFF + swz256(row, col * 2)) = u8.v;
    }
    #pragma unroll
    for (int it = 0; it < 3; ++it) {
        int base = (it * 512 + tid) * 8;
        int row = base >> 7, col = base & 127;
        int sec = row >> 5, r5 = row & 31;
        const float* wp = qkv_w + ((sec * 128 + h * 32 + r5) * DIM + col);
        float4 f0 = *(const float4*)(wp);
        float4 f1 = *(const float4*)(wp + 4);
        union { bf16x8 v; __bf16 e[8]; } u8;
        u8.e[0] = (__bf16)f0.x; u8.e[1] = (__bf16)f0.y; u8.e[2] = (__bf16)f0.z; u8.e[3] = (__bf16)f0.w;
        u8.e[4] = (__bf16)f1.x; u8.e[5] = (__bf16)f1.y; u8.e[6] = (__bf16)f1.z; u8.e[7] = (__bf16)f1.w;
        *(bf16x8*)(smem + W_OFF + swz256(row, col * 2)) = u8.v;
    }
    __syncthreads();

    const float SCALE = 0.17677669529663687f;
    #pragma unroll
    for (int mi = 0; mi < 2; ++mi) {
        int mt = w * 2 + mi;
        bf16x8 xa[4];
        #pragma unroll
        for (int kk = 0; kk < 4; ++kk)
            xa[kk] = *(bf16x8*)(smem + X_OFF + swz256(mt * 16 + lr, kk * 64 + lg * 16));
        #pragma unroll
        for (int nt = 0; nt < 6; ++nt) {
            f32x4 acc = {0.f, 0.f, 0.f, 0.f};
            #pragma unroll
            for (int kk = 0; kk < 4; ++kk) {
                bf16x8 wb = *(bf16x8*)(smem + W_OFF + swz256(nt * 16 + lr, kk * 64 + lg * 16));
                acc = __builtin_amdgcn_mfma_f32_16x16x32_bf16(xa[kk], wb, acc, 0, 0, 0);
            }
            int sec = nt >> 1;
            int d = (nt & 1) * 16 + lr;
            float bias = 0.f;
            if (sec == 0) bias = q_bias[h * 32 + d];
            if (sec == 2) bias = v_bias[h * 32 + d];
            #pragma unroll
            for (int r = 0; r < 4; ++r) {
                int row = mt * 16 + lg * 4 + r;
                float val = acc[r] + bias;
                if (sec == 0) {
                    val *= SCALE;
                    *(__bf16*)(smem + QF_OFF + swz64(row, d * 2)) = (__bf16)val;
                } else if (sec == 1) {
                    *(__bf16*)(smem + KF_OFF + swz64(row, d * 2)) = (__bf16)val;
                } else {
                    *(__bf16*)(smem + VF_OFF + swzV(d, row * 2)) = (__bf16)val;
                }
            }
        }
    }
    __syncthreads();

    bf16x8 qf[2];
    #pragma unroll
    for (int tt = 0; tt < 2; ++tt)
        qf[tt] = *(bf16x8*)(smem + QF_OFF + swz64(w * 32 + tt * 16 + lr, lg * 16));

    f32x4 st[2][16];
    #pragma unroll
    for (int kt = 0; kt < 16; ++kt) {
        bf16x8 kf = *(bf16x8*)(smem + KF_OFF + swz64(kt * 16 + lr, lg * 16));
        f32x4 z = {0.f, 0.f, 0.f, 0.f};
        st[0][kt] = __builtin_amdgcn_mfma_f32_16x16x32_bf16(kf, qf[0], z, 0, 0, 0);
        st[1][kt] = __builtin_amdgcn_mfma_f32_16x16x32_bf16(kf, qf[1], z, 0, 0, 0);
    }

    const int w_idx = bb & 63;
    float inv[2];
    #pragma unroll
    for (int tt = 0; tt < 2; ++tt) {
        int rg = w * 32 + tt * 16 + lr;
        float mx = -3.0e38f;
        #pragma unroll
        for (int kt = 0; kt < 16; ++kt) {
            if (MODE == 1) {
                const unsigned short* brow = aux16 + (((size_t)h) << 16) + rg * 256 + lg * 4;
                const float* mrow = mask + (((size_t)w_idx) << 16) + rg * 256 + lg * 4;
                ushort4 c4 = *(const ushort4*)(brow + kt * 16);
                float4 m4 = *(const float4*)(mrow + kt * 16);
                st[tt][kt][0] += bf2f(c4.x) + m4.x;
                st[tt][kt][1] += bf2f(c4.y) + m4.y;
                st[tt][kt][2] += bf2f(c4.z) + m4.z;
                st[tt][kt][3] += bf2f(c4.w) + m4.w;
            } else {
                const float* mrow = mask + (((size_t)w_idx) << 16) + rg * 256 + lg * 4;
                float4 m4 = *(const float4*)(mrow + kt * 16);
                #pragma unroll
                for (int cc = 0; cc < 4; ++cc) {
                    int j = kt * 16 + lg * 4 + cc;
                    float m = (cc == 0) ? m4.x : (cc == 1) ? m4.y : (cc == 2) ? m4.z : m4.w;
                    st[tt][kt][cc] += table[rel_idx(rg, j) * 4 + h] + m;
                }
            }
            mx = fmaxf(mx, fmaxf(fmaxf(st[tt][kt][0], st[tt][kt][1]),
                                 fmaxf(st[tt][kt][2], st[tt][kt][3])));
        }
        mx = fmaxf(mx, __shfl_xor(mx, 16));
        mx = fmaxf(mx, __shfl_xor(mx, 32));
        float sum = 0.f;
        #pragma unroll
        for (int kt = 0; kt < 16; ++kt) {
            #pragma unroll
            for (int cc = 0; cc < 4; ++cc) {
                float e = __expf(st[tt][kt][cc] - mx);
                st[tt][kt][cc] = e;
                sum += e;
            }
        }
        sum += __shfl_xor(sum, 16);
        sum += __shfl_xor(sum, 32);
        inv[tt] = 1.0f / sum;
    }

    char* pbuf = smem + X_OFF + w * 2048;
    f32x4 oacc[2][2];
    #pragma unroll
    for (int tt = 0; tt < 2; ++tt)
        #pragma unroll
        for (int u = 0; u < 2; ++u)
            oacc[tt][u] = (f32x4){0.f, 0.f, 0.f, 0.f};

    #pragma unroll
    for (int s = 0; s < 8; ++s) {
        #pragma unroll
        for (int tt = 0; tt < 2; ++tt) {
            #pragma unroll
            for (int half = 0; half < 2; ++half) {
                f32x4 pv = st[tt][2 * s + half];
                union { bf16x4 v; __bf16 e[4]; } u4;
                u4.e[0] = (__bf16)(pv[0] * inv[tt]);
                u4.e[1] = (__bf16)(pv[1] * inv[tt]);
                u4.e[2] = (__bf16)(pv[2] * inv[tt]);
                u4.e[3] = (__bf16)(pv[3] * inv[tt]);
                *(bf16x4*)(pbuf + swz64(tt * 16 + lr, half * 32 + lg * 8)) = u4.v;
            }
        }
        bf16x8 vf[2];
        #pragma unroll
        for (int u = 0; u < 2; ++u)
            vf[u] = *(bf16x8*)(smem + VF_OFF + swzV(u * 16 + lr, s * 64 + lg * 16));
        #pragma unroll
        for (int tt = 0; tt < 2; ++tt) {
            bf16x8 af = *(bf16x8*)(pbuf + swz64(tt * 16 + lr, lg * 16));
            #pragma unroll
            for (int u = 0; u < 2; ++u)
                oacc[tt][u] = __builtin_amdgcn_mfma_f32_16x16x32_bf16(af, vf[u], oacc[tt][u], 0, 0, 0);
        }
    }

    float* op = out + (((size_t)bb * 256 + w * 32) * 128) + h * 32;
    #pragma unroll
    for (int tt = 0; tt < 2; ++tt)
        #pragma unroll
        for (int u = 0; u < 2; ++u)
            #pragma unroll
            for (int r = 0; r < 4; ++r)
                op[(tt * 16 + lg * 4 + r) * 128 + u * 16 + lr] = oacc[tt][u][r];
}

extern "C" void kernel_launch(void* const* d_in, const int* in_sizes, int n_in,
                              void* d_out, int out_size, void* d_ws, size_t ws_size,
                              hipStream_t stream) {
    const float* x      = (const float*)d_in[0];
    const float* mask   = (const float*)d_in[1];
    const float* qkv_w  = (const float*)d_in[2];
    const float* q_bias = (const float*)d_in[3];
    const float* v_bias = (const float*)d_in[4];
    const float* table  = (const float*)d_in[5];
    float* out = (float*)d_out;
    (void)in_sizes; (void)n_in; (void)out_size;

    if (ws_size >= (size_t)NEED3) {
        char* ws = (char*)d_ws;
        unsigned short* bias   = (unsigned short*)(ws + BIAS_OFF);
        unsigned short* maskbf = (unsigned short*)(ws + MASK_OFF);
        unsigned short* wbf    = (unsigned short*)(ws + WBF_OFF);
        prep_kernel<<<17600, 256, 0, stream>>>(mask, table, qkv_w, bias, maskbf, wbf);
        attn3_kernel<<<2048, 512, 0, stream>>>(x, wbf, q_bias, v_bias, bias, maskbf, out);
        return;
    }

    const size_t NEED_BIAS = (size_t)4 * 256 * 256 * 2;         // 512 KB
    if (ws_size >= NEED_BIAS) {
        unsigned short* bias = (unsigned short*)d_ws;
        bias_kernel<<<1024, 256, 0, stream>>>(table, bias);
        hipFuncSetAttribute((const void*)attn_kernel<1>,
                            hipFuncAttributeMaxDynamicSharedMemorySize, LDS_BYTES);
        attn_kernel<1><<<2048, 512, LDS_BYTES, stream>>>(x, qkv_w, q_bias, v_bias,
                                                         bias, mask, table, out);
    } else {
        hipFuncSetAttribute((const void*)attn_kernel<2>,
                            hipFuncAttributeMaxDynamicSharedMemorySize, LDS_BYTES);
        attn_kernel<2><<<2048, 512, LDS_BYTES, stream>>>(x, qkv_w, q_bias, v_bias,
                                                         nullptr, mask, table, out);
    }
}